// Round 5
// baseline (96.103 us; speedup 1.0000x reference)
//
#include <hip/hip_runtime.h>
#include <hip/hip_bf16.h>
#include <stdint.h>

typedef float f32x4 __attribute__((ext_vector_type(4)));
typedef short s16x8 __attribute__((ext_vector_type(8)));
typedef int   i32x4 __attribute__((ext_vector_type(4)));
typedef unsigned int u32;

#define NNODES 4096
#define INC    256
#define OUTF   256
#define NEG    0.2f
#define SJ     8
#define JL     512          // NNODES / SJ
#define NIT    16           // JL / 32

__device__ __forceinline__ unsigned short f2bf(float f) {
  unsigned u = __float_as_uint(f);
  u += 0x7FFFu + ((u >> 16) & 1u);          // RNE
  return (unsigned short)(u >> 16);
}
__device__ __forceinline__ unsigned encf(float x) {
  unsigned u = __float_as_uint(x);
  return (u & 0x80000000u) ? ~u : (u | 0x80000000u);
}
__device__ __forceinline__ float decf(unsigned e) {
  unsigned u = (e & 0x80000000u) ? (e ^ 0x80000000u) : ~e;
  return __uint_as_float(u);
}

// ---------------------------------------------------------------------------
// Kernel A: h = x @ W (f32). Tile 32n x 64c, BK=32, grid (4 hb, 128 nb),
// 256 threads -> 512 blocks = 2/CU. Writes hT (bf16 [c][n], granule-swizzled
// within each 32-n block: granule g of row c stored at g ^ ((c&3)^((c>>2)&3))),
// el logits (f32), QS packed (bf16 exp(0.2*er) << 16 | bf16 exp(er)),
// atomicMax of global er max per head.
// ---------------------------------------------------------------------------
__global__ __launch_bounds__(256) void k_feat(
    const float* __restrict__ x, const float* __restrict__ W,
    const float* __restrict__ attl, const float* __restrict__ attr,
    unsigned short* __restrict__ hT, float* __restrict__ el_t,
    u32* __restrict__ QS, unsigned* __restrict__ M_enc)
{
  __shared__ float sm[3328];
  float* xs  = sm;          // [32k][36] (32n + pad)
  float* wsl = sm + 1152;   // [32k][68] (64c + pad)
  const int tid = threadIdx.x;
  const int hb = blockIdx.x, nb = blockIdx.y;
  const int n0 = nb * 32, c0 = hb * 64;
  const int ty = tid >> 4, tx = tid & 15;   // n = ty*2+{0,1}, c = tx*4+{0..3}

  float acc[2][4];
#pragma unroll
  for (int r = 0; r < 2; ++r)
#pragma unroll
    for (int j = 0; j < 4; ++j) acc[r][j] = 0.f;

  const int sxn = tid >> 3;        // 0..31 (n)
  const int sxk = (tid & 7) * 4;   // k offset
  const int swk = tid >> 3;        // 0..31 (k)
  const int swc = (tid & 7) * 8;   // c offset

  for (int kc = 0; kc < INC; kc += 32) {
    __syncthreads();
    {
      float4 a = *(const float4*)(x + (size_t)(n0 + sxn) * INC + kc + sxk);
      xs[(sxk + 0) * 36 + sxn] = a.x;
      xs[(sxk + 1) * 36 + sxn] = a.y;
      xs[(sxk + 2) * 36 + sxn] = a.z;
      xs[(sxk + 3) * 36 + sxn] = a.w;
      const float* wp = W + (size_t)(kc + swk) * OUTF + c0 + swc;
      *(float4*)(wsl + swk * 68 + swc)     = *(const float4*)wp;
      *(float4*)(wsl + swk * 68 + swc + 4) = *(const float4*)(wp + 4);
    }
    __syncthreads();
#pragma unroll
    for (int k = 0; k < 32; ++k) {
      float a0 = xs[k * 36 + ty * 2];
      float a1 = xs[k * 36 + ty * 2 + 1];
      float4 b = *(const float4*)(wsl + k * 68 + tx * 4);
      acc[0][0] = fmaf(a0, b.x, acc[0][0]); acc[0][1] = fmaf(a0, b.y, acc[0][1]);
      acc[0][2] = fmaf(a0, b.z, acc[0][2]); acc[0][3] = fmaf(a0, b.w, acc[0][3]);
      acc[1][0] = fmaf(a1, b.x, acc[1][0]); acc[1][1] = fmaf(a1, b.y, acc[1][1]);
      acc[1][2] = fmaf(a1, b.z, acc[1][2]); acc[1][3] = fmaf(a1, b.w, acc[1][3]);
    }
  }

  float4 al = *(const float4*)(attl + c0 + tx * 4);
  float4 ar = *(const float4*)(attr + c0 + tx * 4);
  float pl[2], pr[2];
#pragma unroll
  for (int r = 0; r < 2; ++r) {
    pl[r] = acc[r][0] * al.x + acc[r][1] * al.y + acc[r][2] * al.z + acc[r][3] * al.w;
    pr[r] = acc[r][0] * ar.x + acc[r][1] * ar.y + acc[r][2] * ar.z + acc[r][3] * ar.w;
  }
#pragma unroll
  for (int m = 1; m < 16; m <<= 1) {
#pragma unroll
    for (int r = 0; r < 2; ++r) {
      pl[r] += __shfl_xor(pl[r], m, 64);
      pr[r] += __shfl_xor(pr[r], m, 64);
    }
  }
  if (tx == 0) {
#pragma unroll
    for (int r = 0; r < 2; ++r) {
      el_t[hb * NNODES + n0 + ty * 2 + r] = pl[r];
      float q = __expf(pr[r]);
      float s = __expf(NEG * pr[r]);
      QS[hb * NNODES + n0 + ty * 2 + r] = (u32)f2bf(q) | ((u32)f2bf(s) << 16);
    }
  }
  float mx = fmaxf(pr[0], pr[1]);
  mx = fmaxf(mx, __shfl_xor(mx, 16, 64));
  mx = fmaxf(mx, __shfl_xor(mx, 32, 64));
  if ((tid & 63) == 0) atomicMax(M_enc + hb, encf(mx));

  __syncthreads();
#pragma unroll
  for (int r = 0; r < 2; ++r)
#pragma unroll
    for (int j = 0; j < 4; ++j)
      sm[(tx * 4 + j) * 33 + ty * 2 + r] = acc[r][j];
  __syncthreads();
  {
    const int c = tid >> 2, g = tid & 3;   // c-row 0..63, granule of 8 n
    unsigned v[4];
#pragma unroll
    for (int i = 0; i < 4; ++i) {
      unsigned lo = f2bf(sm[c * 33 + g * 8 + 2 * i]);
      unsigned hi = f2bf(sm[c * 33 + g * 8 + 2 * i + 1]);
      v[i] = lo | (hi << 16);
    }
    const int sw = (c & 3) ^ ((c >> 2) & 3);
    unsigned short* dst = hT + (size_t)(c0 + c) * NNODES + n0 + ((g ^ sw) * 8);
    *(uint4*)dst = make_uint4(v[0], v[1], v[2], v[3]);
  }
}

// ---------------------------------------------------------------------------
// Kernel B: fused masked-softmax + PV. Block = 512 thr = 8 waves:
// wave wid -> head (wid&3), i-chunk (wid>>2) of 16 rows (block covers 32 i).
// hT staged via 4-slot LDS ring (16KB/slot, all 256 channels), fills issued
// 2 iters ahead with global_load_lds; counted vmcnt(8) retires exactly
// iter-k's 2 fills + 2 adj loads. QS loaded ONCE into LDS up-front (8KB,
// broadcast reads). adj in a 4-stage statically-indexed register file under
// #pragma unroll 4 (no rotation movs -> no forced waits).
// w = max(P_i*Q_j, R_i*S_j) exact leaky-softmax factorization; den via
// MFMA against all-ones B. LDS 72KB -> 2 blocks/CU = 4 waves/SIMD.
// ---------------------------------------------------------------------------
__global__ __launch_bounds__(512, 4) void k_gat(
    const int* __restrict__ adj, const unsigned short* __restrict__ hT,
    const float* __restrict__ el_t, const u32* __restrict__ QS,
    const unsigned* __restrict__ M_enc,
    float* __restrict__ nump, float* __restrict__ denp)
{
  __shared__ __align__(16) unsigned short hbuf[4][8192];  // 4 x 16KB [256 c][32 j]
  __shared__ __align__(16) u32 qsAll[4 * JL];             // 8KB [4 h][JL j]

  const int tid = threadIdx.x;
  const int wid = tid >> 6, lane = tid & 63;
  const int l15 = lane & 15, lg = lane >> 4;
  const int h  = wid & 3;
  const int ic = wid >> 2;
  const int i0 = blockIdx.x * 32 + ic * 16;
  const int js = blockIdx.y;
  const int j0 = js * JL;
  const int irow = i0 + l15;
  const int sw_l = (l15 & 3) ^ ((l15 >> 2) & 3);

  const float el = el_t[h * NNODES + irow];
  const float M  = decf(M_enc[h]);
  const float sE = el + M;
  const float mih = fmaxf(sE, NEG * sE);   // >= every masked score for row i
  const float P = __expf(el - mih);
  const float R = __expf(NEG * el - mih);

  // fill sources (per-lane global addresses; LDS dests wave-uniform + lane*16)
  const unsigned short* hsrc = hT + (size_t)(wid * 16 + (lane >> 2)) * NNODES + j0 + (lane & 3) * 8;
  const int*            asrc = adj + (size_t)irow * NNODES + j0 + lg * 8;

  // QS once: 8 waves x 1 instr x 16B/lane = 8KB
  {
    const u32* qs_ = QS + (size_t)(wid >> 1) * NNODES + j0 + (wid & 1) * 256 + lane * 4;
    __builtin_amdgcn_global_load_lds(qs_, &qsAll[wid * 256], 16, 0, 0);
  }

  f32x4 acc[4];
  f32x4 accd = {0.f, 0.f, 0.f, 0.f};
#pragma unroll
  for (int c = 0; c < 4; ++c) acc[c] = (f32x4){0.f, 0.f, 0.f, 0.f};
  s16x8 ones;
#pragma unroll
  for (int e = 0; e < 8; ++e) ones[e] = (short)0x3F80;  // bf16 1.0

  i32x4 aS[4][2];

#define HFILL(T, SLOT) do {                                                      \
    const unsigned short* hs_ = hsrc + (size_t)(T) * 32;                         \
    __builtin_amdgcn_global_load_lds(hs_, &hbuf[SLOT][wid * 512], 16, 0, 0);     \
    __builtin_amdgcn_global_load_lds(hs_ + (size_t)128 * NNODES,                 \
                                     &hbuf[SLOT][4096 + wid * 512], 16, 0, 0);   \
  } while (0)

  // prologue: groups [F0 a0][F1 a1]
  HFILL(0, 0);
  aS[0][0] = *(const i32x4*)(asrc);
  aS[0][1] = *(const i32x4*)(asrc + 4);
  HFILL(1, 1);
  aS[1][0] = *(const i32x4*)(asrc + 32);
  aS[1][1] = *(const i32x4*)(asrc + 36);

  for (int kb = 0; kb < NIT; kb += 4) {
#pragma unroll
    for (int u = 0; u < 4; ++u) {
      const int k = kb + u;
      const int t2 = (k + 2 < NIT) ? (k + 2) : (NIT - 1);
      HFILL(t2, (u + 2) & 3);
      {
        const int* ap = asrc + t2 * 32;
        aS[(u + 2) & 3][0] = *(const i32x4*)(ap);
        aS[(u + 2) & 3][1] = *(const i32x4*)(ap + 4);
      }
      // newest 8 VMEM = {F(k+1),a(k+1),F(k+2),a(k+2)} -> F(k),a(k) retired
      asm volatile("s_waitcnt vmcnt(8)" ::: "memory");
      __builtin_amdgcn_s_barrier();

      const unsigned short* lb = &hbuf[u][(h * 64 + l15) * 32 + ((lg ^ sw_l) * 8)];
      s16x8 b0 = *(const s16x8*)(lb);
      s16x8 b1 = *(const s16x8*)(lb + 16 * 32);
      s16x8 b2 = *(const s16x8*)(lb + 32 * 32);
      s16x8 b3 = *(const s16x8*)(lb + 48 * 32);
      const u32* qrow = &qsAll[h * JL + k * 32 + lg * 8];
      i32x4 q0 = *(const i32x4*)(qrow);
      i32x4 q1 = *(const i32x4*)(qrow + 4);

      const i32x4 a0 = aS[u][0], a1 = aS[u][1];
      float w[8];
#pragma unroll
      for (int e = 0; e < 4; ++e) {
        u32 m0 = (a0[e] > 0) ? (u32)q0[e] : 0u;
        u32 m1 = (a1[e] > 0) ? (u32)q1[e] : 0u;
        float qq0 = __uint_as_float(m0 << 16);
        float ss0 = __uint_as_float(m0 & 0xffff0000u);
        float qq1 = __uint_as_float(m1 << 16);
        float ss1 = __uint_as_float(m1 & 0xffff0000u);
        w[e]     = fmaxf(P * qq0, R * ss0);
        w[e + 4] = fmaxf(P * qq1, R * ss1);
      }
      union { u32 uu[4]; s16x8 v; } af;
#pragma unroll
      for (int p = 0; p < 4; ++p)
        asm("v_cvt_pk_bf16_f32 %0, %1, %2" : "=v"(af.uu[p]) : "v"(w[2 * p]), "v"(w[2 * p + 1]));

      acc[0] = __builtin_amdgcn_mfma_f32_16x16x32_bf16(af.v, b0,   acc[0], 0, 0, 0);
      acc[1] = __builtin_amdgcn_mfma_f32_16x16x32_bf16(af.v, b1,   acc[1], 0, 0, 0);
      acc[2] = __builtin_amdgcn_mfma_f32_16x16x32_bf16(af.v, b2,   acc[2], 0, 0, 0);
      acc[3] = __builtin_amdgcn_mfma_f32_16x16x32_bf16(af.v, b3,   acc[3], 0, 0, 0);
      accd   = __builtin_amdgcn_mfma_f32_16x16x32_bf16(af.v, ones, accd,   0, 0, 0);
    }
  }
#undef HFILL

  // C/D layout: col = lane&15, row = (lane>>4)*4 + reg
  const int orow = i0 + lg * 4;
  float* np = nump + ((size_t)js * NNODES + orow) * OUTF + h * 64 + l15;
#pragma unroll
  for (int c = 0; c < 4; ++c)
#pragma unroll
    for (int r = 0; r < 4; ++r)
      np[r * OUTF + c * 16] = acc[c][r];

  if (l15 == 0) {
    float* dp = denp + ((size_t)js * NNODES + orow) * 4 + h;
#pragma unroll
    for (int r = 0; r < 4; ++r) dp[r * 4] = accd[r];
  }
}

// ---------------------------------------------------------------------------
// Kernel C: sum j-split partials, divide by den, add bias.
// ---------------------------------------------------------------------------
__global__ __launch_bounds__(256) void k_div(
    const float* __restrict__ nump, const float* __restrict__ denp,
    const float* __restrict__ bias, float* __restrict__ out, int sj)
{
  const int q  = blockIdx.x * 256 + threadIdx.x;  // float4 index
  const int n  = q >> 6;
  const int c4 = (q & 63) * 4;
  const int h  = c4 >> 6;
  f32x4 s = {0.f, 0.f, 0.f, 0.f};
  float d = 0.f;
  for (int t = 0; t < sj; ++t) {
    s += *(const f32x4*)(nump + ((size_t)t * NNODES + n) * OUTF + c4);
    d += denp[((size_t)t * NNODES + n) * 4 + h];
  }
  f32x4 b = *(const f32x4*)(bias + c4);
  float r = __builtin_amdgcn_rcpf(d);
  f32x4 o = s * r + b;
  *(f32x4*)(out + (size_t)n * OUTF + c4) = o;
}

extern "C" void kernel_launch(void* const* d_in, const int* in_sizes, int n_in,
                              void* d_out, int out_size, void* d_ws, size_t ws_size,
                              hipStream_t stream)
{
  const float* x    = (const float*)d_in[0];
  const int*   adj  = (const int*)d_in[1];
  const float* W    = (const float*)d_in[2];
  const float* attl = (const float*)d_in[3];
  const float* attr = (const float*)d_in[4];
  const float* bias = (const float*)d_in[5];
  float* out = (float*)d_out;
  char*  ws  = (char*)d_ws;

  // workspace layout
  unsigned short* hT  = (unsigned short*)ws;                        // 2 MB
  float*    el_t  = (float*)(ws + (2u << 20));                      // 64 KB
  u32*      QS    = (u32*)(ws + (2u << 20) + (64u << 10));          // 64 KB
  unsigned* M_enc = (unsigned*)(ws + (2u << 20) + (128u << 10));    // 16 B
  float*    denp  = (float*)(ws + (2u << 20) + (192u << 10));       // <=512 KB
  const size_t nbase = (3u << 20);
  float* nump = (float*)(ws + nbase);                               // SJ x 4MB

  hipMemsetAsync(M_enc, 0, 16, stream);
  k_feat<<<dim3(4, 128), 256, 0, stream>>>(x, W, attl, attr, hT, el_t, QS, M_enc);
  k_gat<<<dim3(128, SJ), 512, 0, stream>>>(adj, hT, el_t, QS, M_enc, nump, denp);
  k_div<<<dim3(1024), 256, 0, stream>>>(nump, denp, bias, out, SJ);
}